// Round 1
// baseline (376.059 us; speedup 1.0000x reference)
//
#include <hip/hip_runtime.h>
#include <hip/hip_bf16.h>

typedef short short8 __attribute__((ext_vector_type(8)));
typedef unsigned short ushort8v __attribute__((ext_vector_type(8)));
typedef float f32x4 __attribute__((ext_vector_type(4)));

#define D_DIM 2048
#define KTOT 4096      // x|h concatenated along K
#define M_TOT 8192     // B*S

// ---------------- helpers ----------------

__device__ __forceinline__ unsigned short f2bf(float f) {
    union { float f; unsigned u; } c; c.f = f;
    unsigned u = c.u;
    u += 0x7fffu + ((u >> 16) & 1u);   // round-to-nearest-even
    return (unsigned short)(u >> 16);
}

__device__ __forceinline__ float fast_tanh(float x) {
    float ax = fabsf(x);
    float ez = __expf(2.0f * fminf(ax, 15.0f));
    float t = (ez - 1.0f) / (ez + 1.0f);
    return copysignf(t, x);
}

#define GLOAD_LDS16(g, l)                                                     \
    __builtin_amdgcn_global_load_lds(                                         \
        (const __attribute__((address_space(1))) void*)(g),                   \
        (__attribute__((address_space(3))) void*)(l), 16, 0, 0)

// ---------------- pack two f32 [R][2048] matrices into bf16 [R][4096] ------

__global__ __launch_bounds__(256)
void pack2(const float* __restrict__ X, const float* __restrict__ H,
           __hip_bfloat16* __restrict__ dst, int total8) {
    int t = blockIdx.x * 256 + threadIdx.x;
    if (t >= total8) return;
    long e0 = (long)t * 8;
    long r  = e0 >> 12;            // / 4096
    int  k  = (int)(e0 & 4095);
    const float* src = (k < D_DIM) ? (X + r * D_DIM + k)
                                   : (H + r * D_DIM + (k - D_DIM));
    float4 v0 = *(const float4*)(src);
    float4 v1 = *(const float4*)(src + 4);
    ushort8v o;
    o[0] = f2bf(v0.x); o[1] = f2bf(v0.y); o[2] = f2bf(v0.z); o[3] = f2bf(v0.w);
    o[4] = f2bf(v1.x); o[5] = f2bf(v1.y); o[6] = f2bf(v1.z); o[7] = f2bf(v1.w);
    *(ushort8v*)(dst + e0) = o;
}

// ---------------- fused dual-gate GEMM -------------------------------------
// A  : bf16 [8192][4096]   (x | h)
// Bi : bf16 [2048][4096]   (Wi | Ui)    Zi = A @ Bi^T + biases
// Bc : bf16 [2048][4096]   (Wc | Uc)    Zc = A @ Bc^T + biases
// Cout[m][n] = exp(Zi) * tanh(Zc)

#define BM 128
#define BN 128
#define BK 64

__global__ __launch_bounds__(256, 2)
void gemm_gates(const __hip_bfloat16* __restrict__ A,
                const __hip_bfloat16* __restrict__ Bi,
                const __hip_bfloat16* __restrict__ Bc,
                const float* __restrict__ bWi, const float* __restrict__ bUi,
                const float* __restrict__ bWc, const float* __restrict__ bUc,
                float* __restrict__ Cout) {
    __shared__ __hip_bfloat16 lds[3 * BM * BK];    // A | Bi | Bc tiles, 48 KiB

    const int tid  = threadIdx.x;
    const int wid  = tid >> 6;
    const int lane = tid & 63;

    // XCD-aware swizzle; nwg = 1024, divisible by 8 -> bijective
    int bid = blockIdx.x;
    bid = (bid & 7) * 128 + (bid >> 3);
    const int tn = (bid & 15) * BN;    // 16 N-tiles
    const int tm = (bid >> 4) * BM;    // 64 M-tiles

    const int wr = (wid >> 1) * 64;    // wave row offset in tile
    const int wc = (wid & 1) * 64;     // wave col offset in tile

    f32x4 acc_i[4][4] = {};
    f32x4 acc_c[4][4] = {};

    const int crow = lane >> 3;        // 0..7 : row within 8-row chunk
    const int ccol = (lane & 7) * 8;   // k offset within BK
    char* ldsB = (char*)lds;

    const int r15 = lane & 15;
    const int kh  = (lane >> 4) * 8;

    for (int k0 = 0; k0 < KTOT; k0 += BK) {
        __syncthreads();
        #pragma unroll
        for (int q = 0; q < 4; ++q) {
            const int ch  = wid * 4 + q;       // 0..15, 1024B chunks
            const int row = ch * 8 + crow;
            const __hip_bfloat16* gA = A  + (size_t)(tm + row) * KTOT + k0 + ccol;
            const __hip_bfloat16* gI = Bi + (size_t)(tn + row) * KTOT + k0 + ccol;
            const __hip_bfloat16* gC = Bc + (size_t)(tn + row) * KTOT + k0 + ccol;
            GLOAD_LDS16(gA, ldsB + ch * 1024);
            GLOAD_LDS16(gI, ldsB + 16384 + ch * 1024);
            GLOAD_LDS16(gC, ldsB + 32768 + ch * 1024);
        }
        __syncthreads();

        const __hip_bfloat16* lA = lds;
        const __hip_bfloat16* lI = lds + BM * BK;
        const __hip_bfloat16* lC = lds + 2 * BM * BK;

        #pragma unroll
        for (int kk = 0; kk < 2; ++kk) {
            const int kc = kk * 32 + kh;
            short8 af[4], fi[4], fc[4];
            #pragma unroll
            for (int m = 0; m < 4; ++m)
                af[m] = *(const short8*)(lA + (wr + m * 16 + r15) * BK + kc);
            #pragma unroll
            for (int n = 0; n < 4; ++n) {
                fi[n] = *(const short8*)(lI + (wc + n * 16 + r15) * BK + kc);
                fc[n] = *(const short8*)(lC + (wc + n * 16 + r15) * BK + kc);
            }
            #pragma unroll
            for (int m = 0; m < 4; ++m)
                #pragma unroll
                for (int n = 0; n < 4; ++n) {
                    acc_i[m][n] = __builtin_amdgcn_mfma_f32_16x16x32_bf16(
                        af[m], fi[n], acc_i[m][n], 0, 0, 0);
                    acc_c[m][n] = __builtin_amdgcn_mfma_f32_16x16x32_bf16(
                        af[m], fc[n], acc_c[m][n], 0, 0, 0);
                }
        }
    }

    // epilogue: Z -> exp(Zi)*tanh(Zc), C/D layout: col = lane&15, row = (lane>>4)*4 + r
    const int rg = lane >> 4;
    #pragma unroll
    for (int n = 0; n < 4; ++n) {
        const int gn = tn + wc + n * 16 + r15;
        const float bi_ = bWi[gn] + bUi[gn];
        const float bc_ = bWc[gn] + bUc[gn];
        #pragma unroll
        for (int m = 0; m < 4; ++m) {
            #pragma unroll
            for (int r = 0; r < 4; ++r) {
                const int gm = tm + wr + m * 16 + rg * 4 + r;
                const float zi = acc_i[m][n][r] + bi_;
                const float zc = acc_c[m][n][r] + bc_;
                Cout[(size_t)gm * D_DIM + gn] = __expf(zi) * fast_tanh(zc);
            }
        }
    }
}

// ---------------- last-timestep o-gate: hbuf[b][e] = sig(Zo)*tanh(c) -------

__global__ __launch_bounds__(256)
void last_gate(const float* __restrict__ x, const float* __restrict__ h,
               const float* __restrict__ Wo, const float* __restrict__ bWo,
               const float* __restrict__ Uo, const float* __restrict__ bUo,
               const float* __restrict__ cfull, float* __restrict__ hbuf) {
    const int o    = blockIdx.x * 4 + (threadIdx.x >> 6);
    const int lane = threadIdx.x & 63;
    const int b = o >> 11, e = o & 2047;
    const float* xr = x  + ((size_t)b * D_DIM + (D_DIM - 1)) * D_DIM;
    const float* hr = h  + ((size_t)b * D_DIM + (D_DIM - 1)) * D_DIM;
    const float* wo = Wo + (size_t)e * D_DIM;
    const float* uo = Uo + (size_t)e * D_DIM;
    float s = 0.0f;
    for (int d = lane; d < D_DIM; d += 64)
        s += xr[d] * wo[d] + hr[d] * uo[d];
    #pragma unroll
    for (int off = 32; off; off >>= 1) s += __shfl_down(s, off);
    if (lane == 0) {
        const float zo  = s + bWo[e] + bUo[e];
        const float sig = 1.0f / (1.0f + __expf(-zo));
        const float cv  = cfull[((size_t)b * D_DIM + (D_DIM - 1)) * D_DIM + e];
        hbuf[o] = sig * fast_tanh(cv);
    }
}

// ---------------- final projection: out[b][p] = hbuf[b] . Wp[p] + bp[p] ----

__global__ __launch_bounds__(256)
void proj(const float* __restrict__ hbuf, const float* __restrict__ Wp,
          const float* __restrict__ bp, float* __restrict__ out) {
    const int o    = blockIdx.x * 4 + (threadIdx.x >> 6);
    const int lane = threadIdx.x & 63;
    const int b = o >> 11, p = o & 2047;
    const float* hv = hbuf + (size_t)b * D_DIM;
    const float* wp = Wp   + (size_t)p * D_DIM;
    float s = 0.0f;
    for (int e = lane; e < D_DIM; e += 64)
        s += hv[e] * wp[e];
    #pragma unroll
    for (int off = 32; off; off >>= 1) s += __shfl_down(s, off);
    if (lane == 0) out[o] = s + bp[p];
}

// ---------------- launch ---------------------------------------------------

extern "C" void kernel_launch(void* const* d_in, const int* in_sizes, int n_in,
                              void* d_out, int out_size, void* d_ws, size_t ws_size,
                              hipStream_t stream) {
    const float* x   = (const float*)d_in[0];
    const float* h   = (const float*)d_in[1];
    const float* Wi  = (const float*)d_in[2];  const float* bWi = (const float*)d_in[3];
    const float* Ui  = (const float*)d_in[4];  const float* bUi = (const float*)d_in[5];
    // Wf/bWf/Uf/bUf (6..9) are dead: f-gate multiplies a zero cell state
    const float* Wc  = (const float*)d_in[10]; const float* bWc = (const float*)d_in[11];
    const float* Uc  = (const float*)d_in[12]; const float* bUc = (const float*)d_in[13];
    const float* Wo  = (const float*)d_in[14]; const float* bWo = (const float*)d_in[15];
    const float* Uo  = (const float*)d_in[16]; const float* bUo = (const float*)d_in[17];
    const float* Wp  = (const float*)d_in[18]; const float* bp  = (const float*)d_in[19];

    float* out = (float*)d_out;               // [0,8192) hidden_state, then c
    char*  ws  = (char*)d_ws;

    __hip_bfloat16* Abf  = (__hip_bfloat16*)ws;                          // 64 MiB
    __hip_bfloat16* Bibf = (__hip_bfloat16*)(ws + ((size_t)64 << 20));   // 16 MiB
    __hip_bfloat16* Bcbf = (__hip_bfloat16*)(ws + ((size_t)80 << 20));   // 16 MiB
    float*          hbuf = (float*)(ws + ((size_t)96 << 20));            // 32 KiB

    // 1) convert/pack to bf16
    pack2<<<16384, 256, 0, stream>>>(x,  h,  Abf,  M_TOT * KTOT / 8);
    pack2<<<4096,  256, 0, stream>>>(Wi, Ui, Bibf, D_DIM * KTOT / 8);
    pack2<<<4096,  256, 0, stream>>>(Wc, Uc, Bcbf, D_DIM * KTOT / 8);

    // 2) fused dual-gate GEMM -> c (writes out+8192 .. end)
    gemm_gates<<<(M_TOT / BM) * (D_DIM / BN), 256, 0, stream>>>(
        Abf, Bibf, Bcbf, bWi, bUi, bWc, bUc, out + 8192);

    // 3) last-timestep o-gate (reads c from out), then 4) projection
    last_gate<<<2048, 256, 0, stream>>>(x, h, Wo, bWo, Uo, bUo, out + 8192,
                                        (float*)hbuf);
    proj<<<2048, 256, 0, stream>>>(hbuf, Wp, bp, out);
}